// Round 7
// baseline (92.650 us; speedup 1.0000x reference)
//
#include <hip/hip_runtime.h>

#define M_TOT 32768
#define K_TOT 768
#define N_TOT 768

typedef int v4i __attribute__((ext_vector_type(4)));
typedef unsigned int v4u __attribute__((ext_vector_type(4)));

#define GLOAD_LDS(g, l) __builtin_amdgcn_global_load_lds( \
    (const __attribute__((address_space(1))) unsigned int*)(g), \
    (__attribute__((address_space(3))) unsigned int*)(l), 16, 0, 0)

// Pack 4 int32 (each holding an int8 value) into one dword of 4 bytes. (verified R2)
__device__ __forceinline__ unsigned pack4(v4i a) {
  unsigned lo = __builtin_amdgcn_perm((unsigned)a.y, (unsigned)a.x, 0x00000400u);
  unsigned hi = __builtin_amdgcn_perm((unsigned)a.w, (unsigned)a.z, 0x00000400u);
  return __builtin_amdgcn_perm(hi, lo, 0x05040100u);
}

// W[k][n] int32 -> W8T[n][k] int8 (transposed, packed)
__global__ __launch_bounds__(256) void pack_w_kernel(const int* __restrict__ W,
                                                     signed char* __restrict__ W8T) {
  __shared__ signed char t[64][72];
  const int k0 = blockIdx.x * 64, n0 = blockIdx.y * 64;
  for (int i = threadIdx.x; i < 4096; i += 256) {
    int k = i >> 6, n = i & 63;
    t[n][k] = (signed char)W[(k0 + k) * N_TOT + n0 + n];
  }
  __syncthreads();
  for (int i = threadIdx.x; i < 4096; i += 256) {
    int n = i >> 6, k = i & 63;
    W8T[(n0 + n) * K_TOT + k0 + k] = t[n][k];
  }
}

// out_i32 = clamp(round((X@W)*alpha + bias))
// BM=128, BN=128, BK=128 -> 6 K-steps (half the barriers of R4/R6).
// 512 thr = 8 waves (4Mx2N), wave tile 32x64; 16 mfma_i32_16x16x64 per iter.
// 128B LDS rows + (r&7)<<4 XOR swizzle => frag ds_read_b128 AND pack
// ds_write_b128 both conflict-free. A: global->reg->pack->LDS, single q[8]
// buffer (pack(k+1) then reissue into freed regs). B: gload_lds ring-3,
// issued 2 iters ahead (L2-hot W8T).
// In-order vmcnt ledger (stage = 8 A dwordx4 + 2 B gload_lds):
//   steady TOP = vmcnt(10): entering [B(k+1)x2, A(k+1)x8] (+unretired B(k))
//                -> drains B(k) for this iter's MFMA.
//   steady MID = vmcnt(2):  [B(k+1)2, A(k+1)8, B(k+2)2] -> drains A(k+1)
//                (and B(k+1), early but harmless), leaves B(k+2).
__global__ __launch_bounds__(512, 4) void gemm_i8_kernel(
    const int* __restrict__ X, const signed char* __restrict__ W8T,
    const float* __restrict__ bias, const float* __restrict__ alpha_p,
    int* __restrict__ out) {
  __shared__ __align__(16) signed char Abuf[2][16384];
  __shared__ __align__(16) signed char Bbuf[3][16384];

  // Bijective XCD-chunked swizzle: 1536 wgs = 8 XCDs x 192; nt fast so the 6
  // sibling N-tiles of one X M-panel share that XCD's L2.
  const int d = blockIdx.x;
  const int t = (d & 7) * 192 + (d >> 3);
  const int mt = t / 6, nt = t - mt * 6;
  const int row0 = mt << 7, col0 = nt << 7;

  const int tid = threadIdx.x;
  const int lane = tid & 63;
  const int wave = tid >> 6;              // 0..7
  const int wr = wave >> 1, wc = wave & 1;
  const int fr = lane & 15, fg = lane >> 4;
  const int fsw = (fr & 7) << 4;          // frag XOR swizzle (row&7 == fr&7)

  // A: thread covers row tid>>2, int32-col window (tid&3)*32 .. +31.
  const int arow = tid >> 2;              // 0..127
  const int acolw = (tid & 3) << 5;       // int32 col base
  const int* Xbase = X + (row0 + arow) * K_TOT + acolw;
  const int awsw = (arow & 7) << 4;
  const int aoff0 = arow * 128 + ((acolw + 0) ^ awsw);   // int8 col == int32 col
  const int aoff1 = arow * 128 + ((acolw + 16) ^ awsw);

  // B: chunk c = h*512 + tid covers row c>>3, 16B slot c&7; source
  // pre-swizzled so linear LDS dest + swizzled frag read agree (rule #21).
  int bsrc[2], bdst[2];
#pragma unroll
  for (int h = 0; h < 2; ++h) {
    int c = h * 512 + tid;
    int r = c >> 3, slot = c & 7;
    bsrc[h] = (col0 + r) * K_TOT + ((slot << 4) ^ ((r & 7) << 4));
    bdst[h] = h * 8192 + wave * 1024;     // wave-uniform base; HW adds lane*16
  }

  v4i q[8];
  const v4i zero = {0, 0, 0, 0};
  v4i acc[2][4];
#pragma unroll
  for (int m = 0; m < 2; ++m)
#pragma unroll
    for (int n = 0; n < 4; ++n) acc[m][n] = zero;

#define ISSUE_A(ks)                                                      \
  do {                                                                   \
    const int* _p = Xbase + (ks) * 128;                                  \
    _Pragma("unroll") for (int j = 0; j < 8; ++j)                        \
        q[j] = *(const v4i*)(_p + ((j & 3) << 2) + ((j >> 2) << 4));     \
  } while (0)

#define ISSUE_B(ks)                                                      \
  do {                                                                   \
    const signed char* _w = W8T + (ks) * 128;                            \
    signed char* _lb = Bbuf[(ks) % 3];                                   \
    GLOAD_LDS(_w + bsrc[0], _lb + bdst[0]);                              \
    GLOAD_LDS(_w + bsrc[1], _lb + bdst[1]);                              \
  } while (0)

#define PACK_WRITE_A(ss)                                                 \
  do {                                                                   \
    signed char* _ab = Abuf[(ss) & 1];                                   \
    unsigned _pk[8];                                                     \
    _Pragma("unroll") for (int j = 0; j < 8; ++j) _pk[j] = pack4(q[j]);  \
    v4u _w0 = {_pk[0], _pk[1], _pk[2], _pk[3]};                          \
    v4u _w1 = {_pk[4], _pk[5], _pk[6], _pk[7]};                          \
    *(v4u*)&_ab[aoff0] = _w0;                                            \
    *(v4u*)&_ab[aoff1] = _w1;                                            \
  } while (0)

#define FRAGS_K(ks, kk)                                                  \
  do {                                                                   \
    v4i af[2], bf[4];                                                    \
    const signed char* _ab = Abuf[(ks) & 1];                             \
    const signed char* _bb = Bbuf[(ks) % 3];                             \
    const int _kb = ((kk) * 64 + fg * 16) ^ fsw;                         \
    _Pragma("unroll") for (int m = 0; m < 2; ++m)                        \
        af[m] = *(const v4i*)&_ab[(wr * 32 + m * 16 + fr) * 128 + _kb];  \
    _Pragma("unroll") for (int n = 0; n < 4; ++n)                        \
        bf[n] = *(const v4i*)&_bb[(wc * 64 + n * 16 + fr) * 128 + _kb];  \
    __builtin_amdgcn_s_setprio(1);                                       \
    _Pragma("unroll") for (int m = 0; m < 2; ++m)                        \
        _Pragma("unroll") for (int n = 0; n < 4; ++n)                    \
            acc[m][n] = __builtin_amdgcn_mfma_i32_16x16x64_i8(           \
                af[m], bf[n], acc[m][n], 0, 0, 0);                       \
    __builtin_amdgcn_s_setprio(0);                                       \
  } while (0)

  // GITER: top-wait (B(ks) retired; own+others ds_writes via lgkm+barrier)
  // -> issue B(ks+2) -> MFMA half kk=0 -> mid-wait (A(ks+1) regs) -> pack
  // -> issue A(ks+2) into freed q -> MFMA half kk=1.
#define GITER(ks, TOPW, MIDW, DOB, DOA, DOPACK)                          \
  do {                                                                   \
    asm volatile("s_waitcnt vmcnt(" TOPW ") lgkmcnt(0)" ::: "memory");   \
    __builtin_amdgcn_s_barrier();                                        \
    if (DOB) ISSUE_B((ks) + 2);                                          \
    FRAGS_K(ks, 0);                                                      \
    if (DOPACK) {                                                        \
      asm volatile("s_waitcnt vmcnt(" MIDW ")" ::: "memory");            \
      PACK_WRITE_A((ks) + 1);                                            \
      if (DOA) ISSUE_A((ks) + 2);                                        \
    }                                                                    \
    FRAGS_K(ks, 1);                                                      \
  } while (0)

  // Prologue: A(0)x8, B(0)x2, B(1)x2 in flight; vmcnt(4) drains A(0) only;
  // pack A(0); issue A(1). Entering iter0: [B(0)2, B(1)2, A(1)8].
  ISSUE_A(0);
  ISSUE_B(0);
  ISSUE_B(1);
  asm volatile("s_waitcnt vmcnt(4)" ::: "memory");
  PACK_WRITE_A(0);
  ISSUE_A(1);

  GITER(0, "10", "2", 1, 1, 1);
  GITER(1, "10", "2", 1, 1, 1);
  GITER(2, "10", "2", 1, 1, 1);
  GITER(3, "10", "2", 1, 1, 1);
  GITER(4, "10", "0", 0, 0, 1);   // mid vmcnt(0): fully drain A(5) (newest)
  GITER(5, "0", "0", 0, 0, 0);

  // Epilogue: C/D layout col = lane&15, row = (lane>>4)*4 + reg. Output int32.
  const float alpha = *alpha_p;
  float bv[4];
#pragma unroll
  for (int n = 0; n < 4; ++n) bv[n] = bias[col0 + wc * 64 + n * 16 + fr];

#pragma unroll
  for (int m = 0; m < 2; ++m) {
    int orow = row0 + wr * 32 + m * 16 + fg * 4;
#pragma unroll
    for (int n = 0; n < 4; ++n) {
      int ocol = col0 + wc * 64 + n * 16 + fr;
      int* po = out + orow * N_TOT + ocol;
#pragma unroll
      for (int r = 0; r < 4; ++r) {
        float v = rintf((float)acc[m][n][r] * alpha + bv[n]);
        v = fminf(127.f, fmaxf(-128.f, v));
        po[r * N_TOT] = (int)v;
      }
    }
  }
}

extern "C" void kernel_launch(void* const* d_in, const int* in_sizes, int n_in,
                              void* d_out, int out_size, void* d_ws, size_t ws_size,
                              hipStream_t stream) {
  const int* X = (const int*)d_in[0];        // [4,8192,768] int8 promoted to int32
  const int* W = (const int*)d_in[1];        // [768,768] int8 promoted to int32
  const float* bias = (const float*)d_in[2]; // [1,768] fp16 promoted to float32
  const float* alpha = (const float*)d_in[3];
  int* out = (int*)d_out;                    // int8 output promoted to int32
  signed char* W8T = (signed char*)d_ws;     // 768*768 = 589,824 B scratch

  dim3 pg(K_TOT / 64, N_TOT / 64);
  pack_w_kernel<<<pg, 256, 0, stream>>>(W, W8T);
  gemm_i8_kernel<<<(M_TOT / 128) * (N_TOT / 128), 512, 0, stream>>>(X, W8T, bias, alpha, out);
}